// Round 1
// baseline (256.059 us; speedup 1.0000x reference)
//
#include <hip/hip_runtime.h>

// ---------- types ----------
typedef __attribute__((ext_vector_type(8))) __bf16 bf16x8;
typedef __attribute__((ext_vector_type(4))) float f32x4;
typedef __attribute__((ext_vector_type(4))) unsigned short us4;
typedef __attribute__((address_space(3))) void* as3vp;
typedef const __attribute__((address_space(1))) void* as1vp;

#define GLOAD_LDS16(g, l) __builtin_amdgcn_global_load_lds((as1vp)(g), (as3vp)(l), 16, 0, 0)

__device__ __forceinline__ unsigned short f2bf(float f) {
  unsigned u = __builtin_bit_cast(unsigned, f);
  u += 0x7FFFu + ((u >> 16) & 1u);   // RNE
  return (unsigned short)(u >> 16);
}

// ---------- f32 -> bf16 (vectorized) ----------
__global__ void cvt_f32_bf16(const float* __restrict__ x, unsigned short* __restrict__ y, int n4) {
  int i = blockIdx.x * 256 + threadIdx.x;
  if (i >= n4) return;
  float4 v = ((const float4*)x)[i];
  us4 o;
  o.x = f2bf(v.x); o.y = f2bf(v.y); o.z = f2bf(v.z); o.w = f2bf(v.w);
  ((us4*)y)[i] = o;
}

// ---------- W (KxN f32) -> WT (NxK bf16), 32x32 LDS tiles ----------
__global__ void transpose_w_bf16(const float* __restrict__ W, unsigned short* __restrict__ WT,
                                 int K, int N) {
  __shared__ float t[32][33];
  const int tx = threadIdx.x & 31, ty = threadIdx.x >> 5;
  const int n0 = blockIdx.x * 32, k0 = blockIdx.y * 32;
#pragma unroll
  for (int i = 0; i < 32; i += 8)
    t[ty + i][tx] = W[(size_t)(k0 + ty + i) * N + n0 + tx];
  __syncthreads();
#pragma unroll
  for (int i = 0; i < 32; i += 8)
    WT[(size_t)(n0 + ty + i) * K + k0 + tx] = f2bf(t[tx][ty + i]);
}

// ---------- GEMM: C(MxN bf16) = A(MxK bf16) @ Bt(NxK bf16)^T + bias ----------
// 128x128 tile, BK=64, 4 waves (2x2), 16x16x32 MFMA, global_load_lds width-16 staging.
// VT_OUT: write V transposed as (B,H,64,SV)  [b=row>>11, sv=row&2047, h=col>>6, d=col&63]
template<int KDIM, bool VT_OUT>
__global__ __launch_bounds__(256)
void gemm_bt(const unsigned short* __restrict__ A,
             const unsigned short* __restrict__ Bt,
             const float* __restrict__ bias,
             unsigned short* __restrict__ C, int N) {
  __shared__ unsigned short sA[128 * 64];
  __shared__ unsigned short sB[128 * 64];
  const int tid = threadIdx.x, lane = tid & 63, w = tid >> 6;
  const int l15 = lane & 15, lhi = lane >> 4;
  const int wm = w >> 1, wn = w & 1;
  const int row0 = blockIdx.x * 128, col0 = blockIdx.y * 128;

  const f32x4 z = {0.f, 0.f, 0.f, 0.f};
  f32x4 acc[4][4];
#pragma unroll
  for (int m = 0; m < 4; ++m)
#pragma unroll
    for (int n = 0; n < 4; ++n) acc[m][n] = z;

  for (int kt = 0; kt < KDIM; kt += 64) {
    __syncthreads();
#pragma unroll
    for (int i = 0; i < 4; ++i) {
      const int c = i * 256 + w * 64 + lane;   // 16B chunk id, 0..1023
      const int r = c >> 3, kc = (c & 7) * 8;  // tile row, k-col
      GLOAD_LDS16(A + (size_t)(row0 + r) * KDIM + kt + kc, sA + (size_t)(i * 256 + w * 64) * 8);
      GLOAD_LDS16(Bt + (size_t)(col0 + r) * KDIM + kt + kc, sB + (size_t)(i * 256 + w * 64) * 8);
    }
    __syncthreads();
#pragma unroll
    for (int ks = 0; ks < 2; ++ks) {
      const int ko = ks * 32 + lhi * 8;
      bf16x8 af[4], bfr[4];
#pragma unroll
      for (int m = 0; m < 4; ++m) af[m] = *(const bf16x8*)(sA + (wm * 64 + m * 16 + l15) * 64 + ko);
#pragma unroll
      for (int n = 0; n < 4; ++n) bfr[n] = *(const bf16x8*)(sB + (wn * 64 + n * 16 + l15) * 64 + ko);
#pragma unroll
      for (int m = 0; m < 4; ++m)
#pragma unroll
        for (int n = 0; n < 4; ++n)
          acc[m][n] = __builtin_amdgcn_mfma_f32_16x16x32_bf16(af[m], bfr[n], acc[m][n], 0, 0, 0);
    }
  }
  // epilogue: D layout col=lane&15, row=(lane>>4)*4+reg  [measured m89/m91]
#pragma unroll
  for (int n = 0; n < 4; ++n) {
    const int gc = col0 + wn * 64 + n * 16 + l15;
    const float bv = bias[gc];
#pragma unroll
    for (int m = 0; m < 4; ++m) {
      const int gr0 = row0 + wm * 64 + m * 16 + lhi * 4;
#pragma unroll
      for (int r = 0; r < 4; ++r) {
        const unsigned short hv = f2bf(acc[m][n][r] + bv);
        const int gr = gr0 + r;
        if (!VT_OUT) {
          C[(size_t)gr * N + gc] = hv;
        } else {
          C[(((size_t)((gr >> 11) * 16 + (gc >> 6))) << 17) + (size_t)(gc & 63) * 2048 + (gr & 2047)] = hv;
        }
      }
    }
  }
}

// ---------- fused flash attention + pooled gate + blend ----------
// grid (32 qtiles, 16 heads, 2 batch), 256 threads = 4 waves, 16 q-rows/wave, KV tile 64.
__global__ __launch_bounds__(256)
void attn_fused(const unsigned short* __restrict__ Q,   // (B*SQ, 1024) bf16
                const unsigned short* __restrict__ Kb,  // (B*SV, 1024) bf16
                const unsigned short* __restrict__ VT,  // (B,H,64,SV) bf16
                const float* __restrict__ mask,         // (B, SV)
                const float* __restrict__ counts,       // (B)
                const float* __restrict__ gain,         // (H)
                const float* __restrict__ gbias,        // (H)
                const float* __restrict__ pq,           // (B*SQ, 1280) f32
                float* __restrict__ out) {              // (B*SQ, 1280) f32
  __shared__ unsigned short sK[64 * 64];
  __shared__ unsigned short sV[64 * 64];
  __shared__ unsigned short sP[4][16 * 64];
  const int tid = threadIdx.x, lane = tid & 63, w = tid >> 6;
  const int l15 = lane & 15, lhi = lane >> 4;
  const int qt = blockIdx.x, h = blockIdx.y, b = blockIdx.z;
  const int q0 = qt * 64;

  bf16x8 qf[2];
  {
    const size_t qoff = ((size_t)(b * 2048 + q0 + w * 16 + l15)) * 1024 + h * 64 + lhi * 8;
    qf[0] = *(const bf16x8*)(Q + qoff);
    qf[1] = *(const bf16x8*)(Q + qoff + 32);
  }
  const unsigned short* Kbase = Kb + (size_t)(b * 2048) * 1024 + h * 64;
  const unsigned short* Vbase = VT + (((size_t)(b * 16 + h)) << 17);
  const float* mrow = mask + b * 2048;

  const f32x4 z = {0.f, 0.f, 0.f, 0.f};
  f32x4 o_acc[4];
#pragma unroll
  for (int d = 0; d < 4; ++d) o_acc[d] = z;
  float m_r[4], l_r[4], pooled[4];
#pragma unroll
  for (int r = 0; r < 4; ++r) { m_r[r] = -1e30f; l_r[r] = 0.f; pooled[r] = 0.f; }

  for (int kv = 0; kv < 2048; kv += 64) {
    __syncthreads();
#pragma unroll
    for (int i = 0; i < 2; ++i) {
      const int c = i * 256 + w * 64 + lane;   // 0..511
      const int kr = c >> 3, kc = (c & 7) * 8;
      GLOAD_LDS16(Kbase + (size_t)(kv + kr) * 1024 + kc, sK + (i * 256 + w * 64) * 8);
      GLOAD_LDS16(Vbase + (size_t)kr * 2048 + kv + kc, sV + (i * 256 + w * 64) * 8);
    }
    __syncthreads();

    // S = Q K^T (scaled later); lane holds S[lhi*4+r][n*16+l15]
    f32x4 s_acc[4];
#pragma unroll
    for (int n = 0; n < 4; ++n) s_acc[n] = z;
#pragma unroll
    for (int ks = 0; ks < 2; ++ks) {
      const int ko = ks * 32 + lhi * 8;
#pragma unroll
      for (int n = 0; n < 4; ++n) {
        bf16x8 kf = *(const bf16x8*)(sK + (n * 16 + l15) * 64 + ko);
        s_acc[n] = __builtin_amdgcn_mfma_f32_16x16x32_bf16(qf[ks], kf, s_acc[n], 0, 0, 0);
      }
    }
    float mv[4];
#pragma unroll
    for (int n = 0; n < 4; ++n) mv[n] = mrow[kv + n * 16 + l15];

#pragma unroll
    for (int r = 0; r < 4; ++r) {
      float tm = -1e30f;
#pragma unroll
      for (int n = 0; n < 4; ++n) {
        float sv = s_acc[n][r] * 0.125f;          // 1/sqrt(64)
        s_acc[n][r] = sv;
        pooled[r] += sv * mv[n];                  // pre-softmax masked pooled sum
        tm = fmaxf(tm, (mv[n] != 0.f) ? sv : -1e30f);
      }
#pragma unroll
      for (int d = 1; d < 16; d <<= 1) tm = fmaxf(tm, __shfl_xor(tm, d, 64));
      const float mnew = fmaxf(m_r[r], tm);
      const float corr = __expf(m_r[r] - mnew);
      m_r[r] = mnew;
      float lsum = 0.f;
#pragma unroll
      for (int n = 0; n < 4; ++n) {
        float p = (mv[n] != 0.f) ? __expf(s_acc[n][r] - mnew) : 0.f;
        lsum += p;
        sP[w][(lhi * 4 + r) * 64 + n * 16 + l15] = f2bf(p);
      }
      l_r[r] = l_r[r] * corr + lsum;
      o_acc[0][r] *= corr; o_acc[1][r] *= corr; o_acc[2][r] *= corr; o_acc[3][r] *= corr;
    }

    // O += P @ V   (A = own wave's sP rows, B = transposed-V tile)
#pragma unroll
    for (int ks = 0; ks < 2; ++ks) {
      const int ko = ks * 32 + lhi * 8;
      bf16x8 pf = *(const bf16x8*)(sP[w] + l15 * 64 + ko);
#pragma unroll
      for (int d = 0; d < 4; ++d) {
        bf16x8 vf = *(const bf16x8*)(sV + (d * 16 + l15) * 64 + ko);
        o_acc[d] = __builtin_amdgcn_mfma_f32_16x16x32_bf16(pf, vf, o_acc[d], 0, 0, 0);
      }
    }
  }

  // row reductions across the 16 lanes sharing each row
#pragma unroll
  for (int r = 0; r < 4; ++r) {
    float lv = l_r[r], pv = pooled[r];
#pragma unroll
    for (int d = 1; d < 16; d <<= 1) { lv += __shfl_xor(lv, d, 64); pv += __shfl_xor(pv, d, 64); }
    l_r[r] = lv; pooled[r] = pv;
  }
  const float g = gain[h], bb = gbias[h], inv_cnt = 1.f / counts[b];
  float wg[4], invl[4];
#pragma unroll
  for (int r = 0; r < 4; ++r) {
    const float po = pooled[r] * inv_cnt;
    wg[r] = 1.f / (1.f + __expf(-(po * g + bb)));
    invl[r] = 1.f / l_r[r];
  }
  const int sqb = b * 2048 + q0 + w * 16 + lhi * 4;
#pragma unroll
  for (int d = 0; d < 4; ++d) {
    const int col = h * 64 + d * 16 + l15;
#pragma unroll
    for (int r = 0; r < 4; ++r) {
      const size_t o = (size_t)(sqb + r) * 1280 + col;
      const float hval = o_acc[d][r] * invl[r];
      out[o] = pq[o] * (1.f - wg[r]) + hval * wg[r];
    }
  }
}

// ---------- passthrough of pre_query[:, :, 1024:1280] ----------
__global__ void copy_tail(const float* __restrict__ pq, float* __restrict__ out) {
  const int idx = blockIdx.x * 256 + threadIdx.x;  // 0..262143
  const int row = idx >> 6, c4 = idx & 63;
  const size_t off = (size_t)row * 1280 + 1024 + (size_t)c4 * 4;
  *(float4*)(out + off) = *(const float4*)(pq + off);
}

extern "C" void kernel_launch(void* const* d_in, const int* in_sizes, int n_in,
                              void* d_out, int out_size, void* d_ws, size_t ws_size,
                              hipStream_t stream) {
  const float* pre_vk = (const float*)d_in[0];
  const float* pre_q  = (const float*)d_in[1];
  const float* vmask  = (const float*)d_in[2];
  const float* vcnt   = (const float*)d_in[3];
  const float* Wq = (const float*)d_in[4];
  const float* bq = (const float*)d_in[5];
  const float* Wk = (const float*)d_in[6];
  const float* bk = (const float*)d_in[7];
  const float* Wv = (const float*)d_in[8];
  const float* bv = (const float*)d_in[9];
  const float* gain  = (const float*)d_in[10];
  const float* gbias = (const float*)d_in[11];
  float* out = (float*)d_out;

  char* ws = (char*)d_ws;
  unsigned short* pq_bf = (unsigned short*)(ws);              // 4096x1280 bf16
  unsigned short* pv_bf = (unsigned short*)(ws + 10485760);   // 4096x1024
  unsigned short* WqT   = (unsigned short*)(ws + 18874368);   // 1024x1280
  unsigned short* WkT   = (unsigned short*)(ws + 21495808);   // 1024x1024
  unsigned short* WvT   = (unsigned short*)(ws + 23592960);   // 1024x1024
  unsigned short* Qb    = (unsigned short*)(ws + 25690112);   // 4096x1024
  unsigned short* Kbb   = (unsigned short*)(ws + 34078720);   // 4096x1024
  unsigned short* VTb   = (unsigned short*)(ws + 42467328);   // (2,16,64,2048)

  cvt_f32_bf16<<<5120, 256, 0, stream>>>(pre_q, pq_bf, 1310720);
  cvt_f32_bf16<<<4096, 256, 0, stream>>>(pre_vk, pv_bf, 1048576);
  transpose_w_bf16<<<dim3(32, 40), 256, 0, stream>>>(Wq, WqT, 1280, 1024);
  transpose_w_bf16<<<dim3(32, 32), 256, 0, stream>>>(Wk, WkT, 1024, 1024);
  transpose_w_bf16<<<dim3(32, 32), 256, 0, stream>>>(Wv, WvT, 1024, 1024);
  gemm_bt<1280, false><<<dim3(32, 8), 256, 0, stream>>>(pq_bf, WqT, bq, Qb, 1024);
  gemm_bt<1024, false><<<dim3(32, 8), 256, 0, stream>>>(pv_bf, WkT, bk, Kbb, 1024);
  gemm_bt<1024, true ><<<dim3(32, 8), 256, 0, stream>>>(pv_bf, WvT, bv, VTb, 1024);
  attn_fused<<<dim3(32, 16, 2), 256, 0, stream>>>(Qb, Kbb, VTb, vmask, vcnt, gain, gbias, pre_q, out);
  copy_tail<<<1024, 256, 0, stream>>>(pre_q, out);
}

// Round 2
// 151.389 us; speedup vs baseline: 1.6914x; 1.6914x over previous
//
#include <hip/hip_runtime.h>

// ---------- types ----------
typedef __attribute__((ext_vector_type(8))) __bf16 bf16x8;
typedef __attribute__((ext_vector_type(4))) float f32x4;
typedef __attribute__((ext_vector_type(4))) unsigned short us4;
typedef __attribute__((address_space(3))) void* as3vp;
typedef const __attribute__((address_space(1))) void* as1vp;

#define GLOAD_LDS16(g, l) __builtin_amdgcn_global_load_lds((as1vp)(g), (as3vp)(l), 16, 0, 0)

__device__ __forceinline__ unsigned short f2bf(float f) {
  unsigned u = __builtin_bit_cast(unsigned, f);
  u += 0x7FFFu + ((u >> 16) & 1u);   // RNE
  return (unsigned short)(u >> 16);
}

// ---------- f32 -> bf16 (vectorized) ----------
__global__ void cvt_f32_bf16(const float* __restrict__ x, unsigned short* __restrict__ y, int n4) {
  int i = blockIdx.x * 256 + threadIdx.x;
  if (i >= n4) return;
  float4 v = ((const float4*)x)[i];
  us4 o;
  o.x = f2bf(v.x); o.y = f2bf(v.y); o.z = f2bf(v.z); o.w = f2bf(v.w);
  ((us4*)y)[i] = o;
}

// ---------- W (KxN f32) -> WT (NxK bf16), 32x32 LDS tiles ----------
__global__ void transpose_w_bf16(const float* __restrict__ W, unsigned short* __restrict__ WT,
                                 int K, int N) {
  __shared__ float t[32][33];
  const int tx = threadIdx.x & 31, ty = threadIdx.x >> 5;
  const int n0 = blockIdx.x * 32, k0 = blockIdx.y * 32;
#pragma unroll
  for (int i = 0; i < 32; i += 8)
    t[ty + i][tx] = W[(size_t)(k0 + ty + i) * N + n0 + tx];
  __syncthreads();
#pragma unroll
  for (int i = 0; i < 32; i += 8)
    WT[(size_t)(n0 + ty + i) * K + k0 + tx] = f2bf(t[tx][ty + i]);
}

// ---------- GEMM: C(MxN bf16) = A(MxK bf16) @ Bt(NxK bf16)^T + bias ----------
// 128x64 tile, BK=64, 4 waves (2x2 over 64x32 each), XOR-swizzled LDS,
// double-buffered single-barrier K-loop, global_load_lds width-16 staging.
// QSCALE: multiply output by 0.125 (folds the attention 1/sqrt(64)).
// VT_OUT: write V transposed as (B,H,64,SV).
template<int KDIM, bool VT_OUT, bool QSCALE>
__global__ __launch_bounds__(256, 2)
void gemm_bt(const unsigned short* __restrict__ A,
             const unsigned short* __restrict__ Bt,
             const float* __restrict__ bias,
             unsigned short* __restrict__ C, int N) {
  __shared__ unsigned short sA[2][128 * 64];
  __shared__ unsigned short sB[2][64 * 64];
  const int tid = threadIdx.x, lane = tid & 63, w = tid >> 6;
  const int l15 = lane & 15, lhi = lane >> 4;
  const int wm = w >> 1, wn = w & 1;
  const int row0 = blockIdx.x * 128, col0 = blockIdx.y * 64;

  const f32x4 z = {0.f, 0.f, 0.f, 0.f};
  f32x4 acc[4][2];
#pragma unroll
  for (int m = 0; m < 4; ++m)
#pragma unroll
    for (int n = 0; n < 2; ++n) acc[m][n] = z;

  auto stage = [&](int buf, int kt) {
#pragma unroll
    for (int i = 0; i < 4; ++i) {
      const int c = i * 256 + w * 64 + lane;           // 0..1023
      const int r = c >> 3, kc = ((c & 7) * 8) ^ ((r & 7) * 8);
      GLOAD_LDS16(A + (size_t)(row0 + r) * KDIM + kt + kc, &sA[buf][0] + (i * 256 + w * 64) * 8);
    }
#pragma unroll
    for (int i = 0; i < 2; ++i) {
      const int c = i * 256 + w * 64 + lane;           // 0..511
      const int r = c >> 3, kc = ((c & 7) * 8) ^ ((r & 7) * 8);
      GLOAD_LDS16(Bt + (size_t)(col0 + r) * KDIM + kt + kc, &sB[buf][0] + (i * 256 + w * 64) * 8);
    }
  };

  const int NT = KDIM / 64;
  stage(0, 0);
  __syncthreads();
  int cur = 0;
  for (int t = 0; t < NT; ++t) {
    if (t + 1 < NT) stage(cur ^ 1, (t + 1) * 64);
    const unsigned short* sAb = &sA[cur][0];
    const unsigned short* sBb = &sB[cur][0];
#pragma unroll
    for (int ks = 0; ks < 2; ++ks) {
      const int koS = (ks * 32 + lhi * 8) ^ ((l15 & 7) * 8);
      bf16x8 af[4], bfr[2];
#pragma unroll
      for (int m = 0; m < 4; ++m) af[m] = *(const bf16x8*)(sAb + (wm * 64 + m * 16 + l15) * 64 + koS);
#pragma unroll
      for (int n = 0; n < 2; ++n) bfr[n] = *(const bf16x8*)(sBb + (wn * 32 + n * 16 + l15) * 64 + koS);
#pragma unroll
      for (int m = 0; m < 4; ++m)
#pragma unroll
        for (int n = 0; n < 2; ++n)
          acc[m][n] = __builtin_amdgcn_mfma_f32_16x16x32_bf16(af[m], bfr[n], acc[m][n], 0, 0, 0);
    }
    __syncthreads();
    cur ^= 1;
  }
  // epilogue: D layout col=lane&15, row=(lane>>4)*4+reg
#pragma unroll
  for (int n = 0; n < 2; ++n) {
    const int gc = col0 + wn * 32 + n * 16 + l15;
    const float bv = bias[gc];
#pragma unroll
    for (int m = 0; m < 4; ++m) {
      const int gr0 = row0 + wm * 64 + m * 16 + lhi * 4;
#pragma unroll
      for (int r = 0; r < 4; ++r) {
        float val = acc[m][n][r] + bv;
        if (QSCALE) val *= 0.125f;
        const unsigned short hv = f2bf(val);
        const int gr = gr0 + r;
        if (!VT_OUT) {
          C[(size_t)gr * N + gc] = hv;
        } else {
          C[(((size_t)((gr >> 11) * 16 + (gc >> 6))) << 17) + (size_t)(gc & 63) * 2048 + (gr & 2047)] = hv;
        }
      }
    }
  }
}

// ---------- fused flash attention + pooled gate + blend ----------
// grid (16 qtiles, 16 heads, 2 batch), 512 threads = 8 waves, 16 q-rows/wave,
// KV tile 64, double-buffered K/V (single barrier/tile), XOR-swizzled LDS,
// additive mask + defer-max (THR=8) softmax. Q is pre-scaled by 1/sqrt(64).
__global__ __launch_bounds__(512, 4)
void attn_fused(const unsigned short* __restrict__ Q,   // (B*SQ, 1024) bf16, pre-scaled
                const unsigned short* __restrict__ Kb,  // (B*SV, 1024) bf16
                const unsigned short* __restrict__ VT,  // (B,H,64,SV) bf16
                const float* __restrict__ mask,         // (B, SV)
                const float* __restrict__ counts,       // (B)
                const float* __restrict__ gain,         // (H)
                const float* __restrict__ gbias,        // (H)
                const float* __restrict__ pq,           // (B*SQ, 1280) f32
                float* __restrict__ out) {              // (B*SQ, 1280) f32
  __shared__ unsigned short sK[2][64 * 64];
  __shared__ unsigned short sV[2][64 * 64];
  __shared__ unsigned short sP[8][16 * 64];
  const int tid = threadIdx.x, lane = tid & 63, w = tid >> 6;
  const int l15 = lane & 15, lhi = lane >> 4;
  const int qt = blockIdx.x, h = blockIdx.y, b = blockIdx.z;
  const int q0 = qt * 128;

  bf16x8 qf[2];
  {
    const size_t qoff = ((size_t)(b * 2048 + q0 + w * 16 + l15)) * 1024 + h * 64 + lhi * 8;
    qf[0] = *(const bf16x8*)(Q + qoff);
    qf[1] = *(const bf16x8*)(Q + qoff + 32);
  }
  const unsigned short* Kbase = Kb + (size_t)(b * 2048) * 1024 + h * 64;
  const unsigned short* Vbase = VT + (((size_t)(b * 16 + h)) << 17);
  const float* mrow = mask + b * 2048;

  const f32x4 z = {0.f, 0.f, 0.f, 0.f};
  f32x4 o_acc[4];
#pragma unroll
  for (int d = 0; d < 4; ++d) o_acc[d] = z;
  float m_r[4], l_r[4], pooled[4];
#pragma unroll
  for (int r = 0; r < 4; ++r) { m_r[r] = -1e30f; l_r[r] = 0.f; pooled[r] = 0.f; }

  auto stage = [&](int buf, int kv) {
    const int c = w * 64 + lane;                       // 0..511 (one chunk/lane)
    const int r = c >> 3, kc = ((c & 7) * 8) ^ ((r & 7) * 8);
    GLOAD_LDS16(Kbase + (size_t)(kv + r) * 1024 + kc, &sK[buf][0] + w * 512);
    GLOAD_LDS16(Vbase + (size_t)r * 2048 + kv + kc, &sV[buf][0] + w * 512);
  };

  stage(0, 0);
  __syncthreads();
  int cur = 0;

  for (int t = 0; t < 32; ++t) {
    const int kv = t * 64;
    if (t < 31) stage(cur ^ 1, kv + 64);

    // S = Q K^T (pre-scaled); lane holds S[lhi*4+r][n*16+l15]
    f32x4 s_acc[4];
#pragma unroll
    for (int n = 0; n < 4; ++n) s_acc[n] = z;
#pragma unroll
    for (int ks = 0; ks < 2; ++ks) {
      const int koS = (ks * 32 + lhi * 8) ^ ((l15 & 7) * 8);
#pragma unroll
      for (int n = 0; n < 4; ++n) {
        bf16x8 kf = *(const bf16x8*)(&sK[cur][0] + (n * 16 + l15) * 64 + koS);
        s_acc[n] = __builtin_amdgcn_mfma_f32_16x16x32_bf16(qf[ks], kf, s_acc[n], 0, 0, 0);
      }
    }

    float mv[4], addm[4];
#pragma unroll
    for (int n = 0; n < 4; ++n) {
      mv[n] = mrow[kv + n * 16 + l15];
      addm[n] = (mv[n] != 0.f) ? 0.f : -1e30f;
    }
    // pooled pre-softmax masked sum (on raw scaled scores)
#pragma unroll
    for (int r = 0; r < 4; ++r) {
      float p0 = fmaf(s_acc[0][r], mv[0], fmaf(s_acc[1][r], mv[1], 0.f));
      float p1 = fmaf(s_acc[2][r], mv[2], fmaf(s_acc[3][r], mv[3], 0.f));
      pooled[r] += p0 + p1;
    }
    // additive mask in place
#pragma unroll
    for (int n = 0; n < 4; ++n)
#pragma unroll
      for (int r = 0; r < 4; ++r) s_acc[n][r] += addm[n];

    // defer-max: only reduce+rescale when some lane's partial max exceeds m+8
    float tp[4];
    int need = 0;
#pragma unroll
    for (int r = 0; r < 4; ++r) {
      tp[r] = fmaxf(fmaxf(s_acc[0][r], s_acc[1][r]), fmaxf(s_acc[2][r], s_acc[3][r]));
      need |= (tp[r] > m_r[r] + 8.f);
    }
    if (__any(need)) {
#pragma unroll
      for (int r = 0; r < 4; ++r) {
        float tm = tp[r];
#pragma unroll
        for (int d = 1; d < 16; d <<= 1) tm = fmaxf(tm, __shfl_xor(tm, d, 64));
        const float mnew = fmaxf(m_r[r], tm);
        const float corr = __expf(m_r[r] - mnew);
        m_r[r] = mnew;
        l_r[r] *= corr;
        o_acc[0][r] *= corr; o_acc[1][r] *= corr; o_acc[2][r] *= corr; o_acc[3][r] *= corr;
      }
    }
    // P = exp(S - m), store to swizzled per-wave LDS
#pragma unroll
    for (int r = 0; r < 4; ++r) {
      const int prow = lhi * 4 + r;
      float lsum = 0.f;
#pragma unroll
      for (int n = 0; n < 4; ++n) {
        const float p = __expf(s_acc[n][r] - m_r[r]);
        lsum += p;
        sP[w][prow * 64 + ((n * 16 + l15) ^ ((prow & 7) * 8))] = f2bf(p);
      }
      l_r[r] += lsum;
    }

    // O += P @ V
#pragma unroll
    for (int ks = 0; ks < 2; ++ks) {
      const int koS = (ks * 32 + lhi * 8) ^ ((l15 & 7) * 8);
      bf16x8 pf = *(const bf16x8*)(&sP[w][0] + l15 * 64 + koS);
#pragma unroll
      for (int d = 0; d < 4; ++d) {
        bf16x8 vf = *(const bf16x8*)(&sV[cur][0] + (d * 16 + l15) * 64 + koS);
        o_acc[d] = __builtin_amdgcn_mfma_f32_16x16x32_bf16(pf, vf, o_acc[d], 0, 0, 0);
      }
    }
    __syncthreads();
    cur ^= 1;
  }

  // final row reductions across the 16 lanes sharing each row
#pragma unroll
  for (int r = 0; r < 4; ++r) {
    float lv = l_r[r], pv = pooled[r];
#pragma unroll
    for (int d = 1; d < 16; d <<= 1) { lv += __shfl_xor(lv, d, 64); pv += __shfl_xor(pv, d, 64); }
    l_r[r] = lv; pooled[r] = pv;
  }
  const float g = gain[h], bb = gbias[h], inv_cnt = 1.f / counts[b];
  float wg[4], invl[4];
#pragma unroll
  for (int r = 0; r < 4; ++r) {
    const float po = pooled[r] * inv_cnt;
    wg[r] = 1.f / (1.f + __expf(-(po * g + bb)));
    invl[r] = 1.f / l_r[r];
  }
  const int sqb = b * 2048 + q0 + w * 16 + lhi * 4;
#pragma unroll
  for (int d = 0; d < 4; ++d) {
    const int col = h * 64 + d * 16 + l15;
#pragma unroll
    for (int r = 0; r < 4; ++r) {
      const size_t o = (size_t)(sqb + r) * 1280 + col;
      const float hval = o_acc[d][r] * invl[r];
      out[o] = fmaf(hval - pq[o], wg[r], pq[o]);
    }
  }
}

// ---------- passthrough of pre_query[:, :, 1024:1280] ----------
__global__ void copy_tail(const float* __restrict__ pq, float* __restrict__ out) {
  const int idx = blockIdx.x * 256 + threadIdx.x;  // 0..262143
  const int row = idx >> 6, c4 = idx & 63;
  const size_t off = (size_t)row * 1280 + 1024 + (size_t)c4 * 4;
  *(float4*)(out + off) = *(const float4*)(pq + off);
}

extern "C" void kernel_launch(void* const* d_in, const int* in_sizes, int n_in,
                              void* d_out, int out_size, void* d_ws, size_t ws_size,
                              hipStream_t stream) {
  const float* pre_vk = (const float*)d_in[0];
  const float* pre_q  = (const float*)d_in[1];
  const float* vmask  = (const float*)d_in[2];
  const float* vcnt   = (const float*)d_in[3];
  const float* Wq = (const float*)d_in[4];
  const float* bq = (const float*)d_in[5];
  const float* Wk = (const float*)d_in[6];
  const float* bk = (const float*)d_in[7];
  const float* Wv = (const float*)d_in[8];
  const float* bv = (const float*)d_in[9];
  const float* gain  = (const float*)d_in[10];
  const float* gbias = (const float*)d_in[11];
  float* out = (float*)d_out;

  char* ws = (char*)d_ws;
  unsigned short* pq_bf = (unsigned short*)(ws);              // 4096x1280 bf16
  unsigned short* pv_bf = (unsigned short*)(ws + 10485760);   // 4096x1024
  unsigned short* WqT   = (unsigned short*)(ws + 18874368);   // 1024x1280
  unsigned short* WkT   = (unsigned short*)(ws + 21495808);   // 1024x1024
  unsigned short* WvT   = (unsigned short*)(ws + 23592960);   // 1024x1024
  unsigned short* Qb    = (unsigned short*)(ws + 25690112);   // 4096x1024 (pre-scaled)
  unsigned short* Kbb   = (unsigned short*)(ws + 34078720);   // 4096x1024
  unsigned short* VTb   = (unsigned short*)(ws + 42467328);   // (2,16,64,2048)

  cvt_f32_bf16<<<5120, 256, 0, stream>>>(pre_q, pq_bf, 1310720);
  cvt_f32_bf16<<<4096, 256, 0, stream>>>(pre_vk, pv_bf, 1048576);
  transpose_w_bf16<<<dim3(32, 40), 256, 0, stream>>>(Wq, WqT, 1280, 1024);
  transpose_w_bf16<<<dim3(32, 32), 256, 0, stream>>>(Wk, WkT, 1024, 1024);
  transpose_w_bf16<<<dim3(32, 32), 256, 0, stream>>>(Wv, WvT, 1024, 1024);
  gemm_bt<1280, false, true ><<<dim3(32, 16), 256, 0, stream>>>(pq_bf, WqT, bq, Qb, 1024);
  gemm_bt<1024, false, false><<<dim3(32, 16), 256, 0, stream>>>(pv_bf, WkT, bk, Kbb, 1024);
  gemm_bt<1024, true,  false><<<dim3(32, 16), 256, 0, stream>>>(pv_bf, WvT, bv, VTb, 1024);
  attn_fused<<<dim3(16, 16, 2), 512, 0, stream>>>(Qb, Kbb, VTb, vmask, vcnt, gain, gbias, pre_q, out);
  copy_tail<<<1024, 256, 0, stream>>>(pre_q, out);
}

// Round 3
// 140.351 us; speedup vs baseline: 1.8244x; 1.0786x over previous
//
#include <hip/hip_runtime.h>

// ---------- types ----------
typedef __attribute__((ext_vector_type(8))) __bf16 bf16x8;
typedef __attribute__((ext_vector_type(4))) float f32x4;
typedef __attribute__((ext_vector_type(16))) float f32x16;
typedef __attribute__((ext_vector_type(4))) unsigned short us4;
typedef __attribute__((ext_vector_type(4))) unsigned int u32x4;
typedef __attribute__((address_space(3))) void* as3vp;
typedef const __attribute__((address_space(1))) void* as1vp;

#define GLOAD_LDS16(g, l) __builtin_amdgcn_global_load_lds((as1vp)(g), (as3vp)(l), 16, 0, 0)

#if __has_builtin(__builtin_amdgcn_exp2f)
#define EXP2(x) __builtin_amdgcn_exp2f(x)
#else
#define EXP2(x) __expf((x) * 0.6931471805599453f)
#endif

__device__ __forceinline__ unsigned short f2bf(float f) {
  unsigned u = __builtin_bit_cast(unsigned, f);
  u += 0x7FFFu + ((u >> 16) & 1u);   // RNE
  return (unsigned short)(u >> 16);
}

__device__ __forceinline__ unsigned int pkbf(float a, float b) {
  unsigned int r;
  asm("v_cvt_pk_bf16_f32 %0, %1, %2" : "=v"(r) : "v"(a), "v"(b));
  return r;
}

// ---------- f32 -> bf16 (vectorized) ----------
__global__ void cvt_f32_bf16(const float* __restrict__ x, unsigned short* __restrict__ y, int n4) {
  int i = blockIdx.x * 256 + threadIdx.x;
  if (i >= n4) return;
  float4 v = ((const float4*)x)[i];
  us4 o;
  o.x = f2bf(v.x); o.y = f2bf(v.y); o.z = f2bf(v.z); o.w = f2bf(v.w);
  ((us4*)y)[i] = o;
}

// ---------- W (KxN f32) -> WT (NxK bf16), 32x32 LDS tiles ----------
__global__ void transpose_w_bf16(const float* __restrict__ W, unsigned short* __restrict__ WT,
                                 int K, int N) {
  __shared__ float t[32][33];
  const int tx = threadIdx.x & 31, ty = threadIdx.x >> 5;
  const int n0 = blockIdx.x * 32, k0 = blockIdx.y * 32;
#pragma unroll
  for (int i = 0; i < 32; i += 8)
    t[ty + i][tx] = W[(size_t)(k0 + ty + i) * N + n0 + tx];
  __syncthreads();
#pragma unroll
  for (int i = 0; i < 32; i += 8)
    WT[(size_t)(n0 + ty + i) * K + k0 + tx] = f2bf(t[tx][ty + i]);
}

// ---------- GEMM: C(MxN bf16) = A(MxK bf16) @ Bt(NxK bf16)^T + bias ----------
// (unchanged from round 2: 128x64 tile, dbuf, XOR-swizzled LDS)
template<int KDIM, bool VT_OUT, bool QSCALE>
__global__ __launch_bounds__(256, 2)
void gemm_bt(const unsigned short* __restrict__ A,
             const unsigned short* __restrict__ Bt,
             const float* __restrict__ bias,
             unsigned short* __restrict__ C, int N) {
  __shared__ unsigned short sA[2][128 * 64];
  __shared__ unsigned short sB[2][64 * 64];
  const int tid = threadIdx.x, lane = tid & 63, w = tid >> 6;
  const int l15 = lane & 15, lhi = lane >> 4;
  const int wm = w >> 1, wn = w & 1;
  const int row0 = blockIdx.x * 128, col0 = blockIdx.y * 64;

  const f32x4 z = {0.f, 0.f, 0.f, 0.f};
  f32x4 acc[4][2];
#pragma unroll
  for (int m = 0; m < 4; ++m)
#pragma unroll
    for (int n = 0; n < 2; ++n) acc[m][n] = z;

  auto stage = [&](int buf, int kt) {
#pragma unroll
    for (int i = 0; i < 4; ++i) {
      const int c = i * 256 + w * 64 + lane;
      const int r = c >> 3, kc = ((c & 7) * 8) ^ ((r & 7) * 8);
      GLOAD_LDS16(A + (size_t)(row0 + r) * KDIM + kt + kc, &sA[buf][0] + (i * 256 + w * 64) * 8);
    }
#pragma unroll
    for (int i = 0; i < 2; ++i) {
      const int c = i * 256 + w * 64 + lane;
      const int r = c >> 3, kc = ((c & 7) * 8) ^ ((r & 7) * 8);
      GLOAD_LDS16(Bt + (size_t)(col0 + r) * KDIM + kt + kc, &sB[buf][0] + (i * 256 + w * 64) * 8);
    }
  };

  const int NT = KDIM / 64;
  stage(0, 0);
  __syncthreads();
  int cur = 0;
  for (int t = 0; t < NT; ++t) {
    if (t + 1 < NT) stage(cur ^ 1, (t + 1) * 64);
    const unsigned short* sAb = &sA[cur][0];
    const unsigned short* sBb = &sB[cur][0];
#pragma unroll
    for (int ks = 0; ks < 2; ++ks) {
      const int koS = (ks * 32 + lhi * 8) ^ ((l15 & 7) * 8);
      bf16x8 af[4], bfr[2];
#pragma unroll
      for (int m = 0; m < 4; ++m) af[m] = *(const bf16x8*)(sAb + (wm * 64 + m * 16 + l15) * 64 + koS);
#pragma unroll
      for (int n = 0; n < 2; ++n) bfr[n] = *(const bf16x8*)(sBb + (wn * 32 + n * 16 + l15) * 64 + koS);
#pragma unroll
      for (int m = 0; m < 4; ++m)
#pragma unroll
        for (int n = 0; n < 2; ++n)
          acc[m][n] = __builtin_amdgcn_mfma_f32_16x16x32_bf16(af[m], bfr[n], acc[m][n], 0, 0, 0);
    }
    __syncthreads();
    cur ^= 1;
  }
#pragma unroll
  for (int n = 0; n < 2; ++n) {
    const int gc = col0 + wn * 32 + n * 16 + l15;
    const float bv = bias[gc];
#pragma unroll
    for (int m = 0; m < 4; ++m) {
      const int gr0 = row0 + wm * 64 + m * 16 + lhi * 4;
#pragma unroll
      for (int r = 0; r < 4; ++r) {
        float val = acc[m][n][r] + bv;
        if (QSCALE) val *= 0.125f;
        const unsigned short hv = f2bf(val);
        const int gr = gr0 + r;
        if (!VT_OUT) {
          C[(size_t)gr * N + gc] = hv;
        } else {
          C[(((size_t)((gr >> 11) * 16 + (gc >> 6))) << 17) + (size_t)(gc & 63) * 2048 + (gr & 2047)] = hv;
        }
      }
    }
  }
}

// ---------- fused flash attention + pooled gate + blend ----------
// grid (16 qtiles, 16 heads, 2 batch), 256 threads = 4 waves, 32 q-rows/wave,
// 32x32x16 MFMA with SWAPPED operands: S^T = mfma(K, Q) so each lane owns one
// q column; softmax fully in-register (T12: cvt_pk + half-exchange), P never
// touches LDS. PV = mfma(V^T, P^T). Mask staged in LDS (broadcast reads).
__global__ __launch_bounds__(256, 2)
void attn_fused(const unsigned short* __restrict__ Q,   // (B*SQ, 1024) bf16, pre-scaled by 0.125
                const unsigned short* __restrict__ Kb,  // (B*SV, 1024) bf16
                const unsigned short* __restrict__ VT,  // (B,H,64,SV) bf16
                const float* __restrict__ mask,         // (B, SV)
                const float* __restrict__ counts,       // (B)
                const float* __restrict__ gain,         // (H)
                const float* __restrict__ gbias,        // (H)
                const float* __restrict__ pq,           // (B*SQ, 1280) f32
                float* __restrict__ out) {              // (B*SQ, 1280) f32
  __shared__ __align__(16) char smem[40960];
  unsigned short* sK = (unsigned short*)smem;            // [2][64*64] bf16, 16 KB
  unsigned short* sV = (unsigned short*)(smem + 16384);  // [2][64*64] bf16, 16 KB
  float* smask = (float*)(smem + 32768);                 // [2048] f32, 8 KB
  float* sOT = (float*)smem;                             // epilogue overlay: wave w at +w*2048 f32

  const int tid = threadIdx.x, lane = tid & 63, w = tid >> 6;
  const int l31 = lane & 31, h5 = lane >> 5;
  const int qt = blockIdx.x, hh = blockIdx.y, b = blockIdx.z;
  const int q0 = qt * 128;
  const int q = q0 + w * 32 + l31;          // this lane's q row

  // stage mask (f32, 2048) into LDS
  {
    const float* mrow = mask + b * 2048;
    GLOAD_LDS16(mrow + tid * 4, (char*)smask + tid * 16);
    GLOAD_LDS16(mrow + 1024 + tid * 4, (char*)smask + 4096 + tid * 16);
  }

  // Q fragments (B-operand): lane l31 = q col, k = d = ks*16 + h5*8 + j
  bf16x8 qf[4];
  {
    const unsigned short* qp = Q + (size_t)(b * 2048 + q) * 1024 + hh * 64 + h5 * 8;
    qf[0] = *(const bf16x8*)(qp);
    qf[1] = *(const bf16x8*)(qp + 16);
    qf[2] = *(const bf16x8*)(qp + 32);
    qf[3] = *(const bf16x8*)(qp + 48);
  }
  const unsigned short* Kbase = Kb + (size_t)(b * 2048) * 1024 + hh * 64;
  const unsigned short* Vbase = VT + (((size_t)(b * 16 + hh)) << 17);

  f32x16 o0, o1, l_vec, pl_vec;
#pragma unroll
  for (int r = 0; r < 16; ++r) { o0[r] = 0.f; o1[r] = 0.f; l_vec[r] = 0.f; pl_vec[r] = 0.f; }
  float m_ = -1e30f;

  auto stage = [&](int buf, int kv) {
#pragma unroll
    for (int i = 0; i < 2; ++i) {
      const int c = i * 256 + tid;                       // 0..511
      const int r = c >> 3, sl = (c & 7) ^ (r & 7);
      GLOAD_LDS16(Kbase + (size_t)(kv + r) * 1024 + sl * 8, (char*)sK + buf * 8192 + c * 16);
      GLOAD_LDS16(Vbase + (size_t)r * 2048 + kv + sl * 8, (char*)sV + buf * 8192 + c * 16);
    }
  };

  // builds a PV B-fragment from 8 per-lane P values via pk + half-exchange
  auto mkfrag = [&](float a0, float a1, float a2, float a3,
                    float a4, float a5, float a6, float a7) -> bf16x8 {
    unsigned int x = pkbf(a0, a1), y = pkbf(a2, a3), z = pkbf(a4, a5), v = pkbf(a6, a7);
    unsigned int sx = (unsigned int)__shfl_xor((int)x, 32, 64);
    unsigned int sy = (unsigned int)__shfl_xor((int)y, 32, 64);
    unsigned int sz = (unsigned int)__shfl_xor((int)z, 32, 64);
    unsigned int sv = (unsigned int)__shfl_xor((int)v, 32, 64);
    u32x4 f;
    f.x = h5 ? sz : x;   // word0: lo lanes kv(0,1) / hi lanes kv(8,9)
    f.y = h5 ? sv : y;   // word1
    f.z = h5 ? z : sx;   // word2
    f.w = h5 ? v : sy;   // word3
    return __builtin_bit_cast(bf16x8, f);
  };

  stage(0, 0);
  __syncthreads();
  int cur = 0;

  for (int t = 0; t < 32; ++t) {
    if (t < 31) stage(cur ^ 1, (t + 1) * 64);
    const char* sKc = (const char*)sK + cur * 8192;
    const char* sVc = (const char*)sV + cur * 8192;

    // S^T = K · Q : rows kv (in regs), cols q (= lane)
    f32x16 s0, s1;
#pragma unroll
    for (int r = 0; r < 16; ++r) { s0[r] = 0.f; s1[r] = 0.f; }
#pragma unroll
    for (int ks = 0; ks < 4; ++ks) {
      const int sl = (((ks * 2 + h5) ^ (l31 & 7)) * 16);
      bf16x8 k0 = *(const bf16x8*)(sKc + l31 * 128 + sl);
      bf16x8 k1 = *(const bf16x8*)(sKc + (32 + l31) * 128 + sl);
      s0 = __builtin_amdgcn_mfma_f32_32x32x16_bf16(k0, qf[ks], s0, 0, 0, 0);
      s1 = __builtin_amdgcn_mfma_f32_32x32x16_bf16(k1, qf[ks], s1, 0, 0, 0);
    }

    // mask values for this lane's kv rows (broadcast LDS reads)
    f32x16 mv0, mv1;
#pragma unroll
    for (int g = 0; g < 4; ++g) {
      f32x4 a = *(const f32x4*)(smask + t * 64 + g * 8 + h5 * 4);
      f32x4 c = *(const f32x4*)(smask + t * 64 + 32 + g * 8 + h5 * 4);
#pragma unroll
      for (int j = 0; j < 4; ++j) { mv0[g * 4 + j] = a[j]; mv1[g * 4 + j] = c[j]; }
    }

    // pooled (pre-softmax masked sum) + additive mask
    pl_vec += s0 * mv0;
    pl_vec += s1 * mv1;
    f32x16 sm0 = s0 + (mv0 * 1e30f - 1e30f);
    f32x16 sm1 = s1 + (mv1 * 1e30f - 1e30f);

    // per-lane max + partner combine; defer-max THR=8
    f32x16 mx;
#pragma unroll
    for (int r = 0; r < 16; ++r) mx[r] = fmaxf(sm0[r], sm1[r]);
    float t8[8];
#pragma unroll
    for (int r = 0; r < 8; ++r) t8[r] = fmaxf(mx[r], mx[r + 8]);
    float t4a = fmaxf(t8[0], t8[4]), t4b = fmaxf(t8[1], t8[5]);
    float t4c = fmaxf(t8[2], t8[6]), t4d = fmaxf(t8[3], t8[7]);
    float tp = fmaxf(fmaxf(t4a, t4b), fmaxf(t4c, t4d));
    tp = fmaxf(tp, __shfl_xor(tp, 32, 64));
    if (__any(tp > m_ + 8.f)) {
      const float mnew = fmaxf(m_, tp);
      const float corr = __expf(m_ - mnew);
      m_ = mnew;
      l_vec *= corr;
      o0 *= corr;
      o1 *= corr;
    }

    // P = exp(S - m) (exp2 form), accumulate l
    const float m2 = m_ * 1.44269504f;
    f32x16 a0 = sm0 * 1.44269504f - m2;
    f32x16 a1 = sm1 * 1.44269504f - m2;
    f32x16 p0, p1;
#pragma unroll
    for (int r = 0; r < 16; ++r) p0[r] = EXP2(a0[r]);
#pragma unroll
    for (int r = 0; r < 16; ++r) p1[r] = EXP2(a1[r]);
    l_vec += p0;
    l_vec += p1;

    // P^T B-fragments in-register (T12)
    bf16x8 pf0 = mkfrag(p0[0], p0[1], p0[2], p0[3], p0[4], p0[5], p0[6], p0[7]);
    bf16x8 pf1 = mkfrag(p0[8], p0[9], p0[10], p0[11], p0[12], p0[13], p0[14], p0[15]);
    bf16x8 pf2 = mkfrag(p1[0], p1[1], p1[2], p1[3], p1[4], p1[5], p1[6], p1[7]);
    bf16x8 pf3 = mkfrag(p1[8], p1[9], p1[10], p1[11], p1[12], p1[13], p1[14], p1[15]);

    // O^T += V^T · P^T
#pragma unroll
    for (int ks = 0; ks < 4; ++ks) {
      const int sl = (((ks * 2 + h5) ^ (l31 & 7)) * 16);
      bf16x8 v0 = *(const bf16x8*)(sVc + l31 * 128 + sl);
      bf16x8 v1 = *(const bf16x8*)(sVc + (32 + l31) * 128 + sl);
      const bf16x8 pf = (ks == 0) ? pf0 : (ks == 1) ? pf1 : (ks == 2) ? pf2 : pf3;
      o0 = __builtin_amdgcn_mfma_f32_32x32x16_bf16(v0, pf, o0, 0, 0, 0);
      o1 = __builtin_amdgcn_mfma_f32_32x32x16_bf16(v1, pf, o1, 0, 0, 0);
    }
    __syncthreads();
    cur ^= 1;
  }

  // horizontal + partner reductions
  float l_s = 0.f, pl_s = 0.f;
  {
    float a[8];
#pragma unroll
    for (int r = 0; r < 8; ++r) a[r] = l_vec[r] + l_vec[r + 8];
    l_s = ((a[0] + a[1]) + (a[2] + a[3])) + ((a[4] + a[5]) + (a[6] + a[7]));
#pragma unroll
    for (int r = 0; r < 8; ++r) a[r] = pl_vec[r] + pl_vec[r + 8];
    pl_s = ((a[0] + a[1]) + (a[2] + a[3])) + ((a[4] + a[5]) + (a[6] + a[7]));
  }
  l_s += __shfl_xor(l_s, 32, 64);
  pl_s += __shfl_xor(pl_s, 32, 64);

  const float g = gain[hh], bb = gbias[hh];
  const float po = pl_s / counts[b];
  const float wgv = 1.f / (1.f + __expf(-(po * g + bb)));
  const float invl = 1.f / l_s;

  __syncthreads();   // all waves done with sK/sV before overlay
  float* myOT = sOT + w * 2048;  // 64x32 f32, XOR-swizzled cols
#pragma unroll
  for (int r = 0; r < 16; ++r) {
    const int d0 = (r & 3) + 8 * (r >> 2) + 4 * h5;
    myOT[d0 * 32 + (l31 ^ (d0 & 31))] = o0[r] * invl;
    const int d1 = d0 + 32;
    myOT[d1 * 32 + (l31 ^ (d1 & 31))] = o1[r] * invl;
  }
  __syncthreads();

  const size_t rowbase = (size_t)(b * 2048 + q0 + w * 32) * 1280 + hh * 64 + lane;
  const float* pqrow = pq + rowbase;
  float* outrow = out + rowbase;
#pragma unroll 4
  for (int i = 0; i < 32; ++i) {
    const float hval = myOT[lane * 32 + (i ^ (lane & 31))];
    const float wgrow = __shfl(wgv, i, 64);
    const float pv = pqrow[(size_t)i * 1280];
    outrow[(size_t)i * 1280] = fmaf(hval - pv, wgrow, pv);
  }
}

// ---------- passthrough of pre_query[:, :, 1024:1280] ----------
__global__ void copy_tail(const float* __restrict__ pq, float* __restrict__ out) {
  const int idx = blockIdx.x * 256 + threadIdx.x;  // 0..262143
  const int row = idx >> 6, c4 = idx & 63;
  const size_t off = (size_t)row * 1280 + 1024 + (size_t)c4 * 4;
  *(float4*)(out + off) = *(const float4*)(pq + off);
}

extern "C" void kernel_launch(void* const* d_in, const int* in_sizes, int n_in,
                              void* d_out, int out_size, void* d_ws, size_t ws_size,
                              hipStream_t stream) {
  const float* pre_vk = (const float*)d_in[0];
  const float* pre_q  = (const float*)d_in[1];
  const float* vmask  = (const float*)d_in[2];
  const float* vcnt   = (const float*)d_in[3];
  const float* Wq = (const float*)d_in[4];
  const float* bq = (const float*)d_in[5];
  const float* Wk = (const float*)d_in[6];
  const float* bk = (const float*)d_in[7];
  const float* Wv = (const float*)d_in[8];
  const float* bv = (const float*)d_in[9];
  const float* gain  = (const float*)d_in[10];
  const float* gbias = (const float*)d_in[11];
  float* out = (float*)d_out;

  char* ws = (char*)d_ws;
  unsigned short* pq_bf = (unsigned short*)(ws);              // 4096x1280 bf16
  unsigned short* pv_bf = (unsigned short*)(ws + 10485760);   // 4096x1024
  unsigned short* WqT   = (unsigned short*)(ws + 18874368);   // 1024x1280
  unsigned short* WkT   = (unsigned short*)(ws + 21495808);   // 1024x1024
  unsigned short* WvT   = (unsigned short*)(ws + 23592960);   // 1024x1024
  unsigned short* Qb    = (unsigned short*)(ws + 25690112);   // 4096x1024 (pre-scaled)
  unsigned short* Kbb   = (unsigned short*)(ws + 34078720);   // 4096x1024
  unsigned short* VTb   = (unsigned short*)(ws + 42467328);   // (2,16,64,2048)

  cvt_f32_bf16<<<5120, 256, 0, stream>>>(pre_q, pq_bf, 1310720);
  cvt_f32_bf16<<<4096, 256, 0, stream>>>(pre_vk, pv_bf, 1048576);
  transpose_w_bf16<<<dim3(32, 40), 256, 0, stream>>>(Wq, WqT, 1280, 1024);
  transpose_w_bf16<<<dim3(32, 32), 256, 0, stream>>>(Wk, WkT, 1024, 1024);
  transpose_w_bf16<<<dim3(32, 32), 256, 0, stream>>>(Wv, WvT, 1024, 1024);
  gemm_bt<1280, false, true ><<<dim3(32, 16), 256, 0, stream>>>(pq_bf, WqT, bq, Qb, 1024);
  gemm_bt<1024, false, false><<<dim3(32, 16), 256, 0, stream>>>(pv_bf, WkT, bk, Kbb, 1024);
  gemm_bt<1024, true,  false><<<dim3(32, 16), 256, 0, stream>>>(pv_bf, WvT, bv, VTb, 1024);
  attn_fused<<<dim3(16, 16, 2), 256, 0, stream>>>(Qb, Kbb, VTb, vmask, vcnt, gain, gbias, pre_q, out);
  copy_tail<<<1024, 256, 0, stream>>>(pre_q, out);
}